// Round 6
// baseline (307.386 us; speedup 1.0000x reference)
//
#include <hip/hip_runtime.h>
#include <math.h>

#define D 2048
#define F 256
#define ALPHA 0.005f
#define STOPTHR 0.005f
#define EPSV 1e-16f
#define RPB 8
#define NBLK 256
#define MAGICV 0x13572468u
#define NGRP 8
#define GRPSZ 32

// LDS: gram phase uses 2 x (128 rows x 136 bf16) = 69632 B; loop phase uses
// 64 KB K rows + red. Request max = 69632 B -> 1 block/CU (grid=256=#CUs,
// all co-resident under a regular launch).
#define LDS_FLOATS 17408
#define BSTRIDE 136  // bf16 row stride: 16B-aligned, rows 2-way bank alias (free)

typedef __attribute__((ext_vector_type(8))) short short8_t;
typedef __attribute__((ext_vector_type(4))) float f32x4;

__device__ __forceinline__ short f2bf(float f) {  // RNE float->bf16
    unsigned x = __float_as_uint(f);
    return (short)((x + 0x7fffu + ((x >> 16) & 1u)) >> 16);
}

// ---- two-level grid barrier: 8 parallel group chains -> root -> gen ----
__device__ __forceinline__ void gbar(unsigned* gcnt, unsigned* rcnt, unsigned* gen,
                                     unsigned& lg) {
    __syncthreads();
    if (threadIdx.x == 0) {
        unsigned g = ++lg;
        int grp = blockIdx.x & (NGRP - 1);
        unsigned a = __hip_atomic_fetch_add(&gcnt[grp * 16], 1u, __ATOMIC_ACQ_REL,
                                            __HIP_MEMORY_SCOPE_AGENT);
        if (a == GRPSZ - 1) {
            __hip_atomic_store(&gcnt[grp * 16], 0u, __ATOMIC_RELAXED, __HIP_MEMORY_SCOPE_AGENT);
            unsigned r = __hip_atomic_fetch_add(rcnt, 1u, __ATOMIC_ACQ_REL,
                                                __HIP_MEMORY_SCOPE_AGENT);
            if (r == NGRP - 1) {
                __hip_atomic_store(rcnt, 0u, __ATOMIC_RELAXED, __HIP_MEMORY_SCOPE_AGENT);
                __hip_atomic_store(gen, g, __ATOMIC_RELEASE, __HIP_MEMORY_SCOPE_AGENT);
            } else {
                while ((int)(__hip_atomic_load(gen, __ATOMIC_ACQUIRE, __HIP_MEMORY_SCOPE_AGENT) - g) < 0) {}
            }
        } else {
            while ((int)(__hip_atomic_load(gen, __ATOMIC_ACQUIRE, __HIP_MEMORY_SCOPE_AGENT) - g) < 0) {}
        }
    }
    __syncthreads();
}

// ---- 128x128 gram tile via bf16 MFMA 16x16x32; K=256 in two 128-slabs ----
// wave w -> 64x64 quadrant (wr,wc); 4x4 fragments of 16x16.
__device__ void gram_mfma(const float* __restrict__ X, const float* __restrict__ st,
                          float* __restrict__ dst, int isK, int ti, int tj,
                          short* __restrict__ Abf, short* __restrict__ Bbf) {
    int bi = ti * 128, bj = tj * 128;
    int tid = threadIdx.x;
    int w = tid >> 6, l = tid & 63;
    int wr = w >> 1, wc = w & 1;
    int quad = l >> 4, l15 = l & 15;
    f32x4 acc[4][4];
    f32x4 zz = {0.0f, 0.0f, 0.0f, 0.0f};
#pragma unroll
    for (int mi = 0; mi < 4; mi++)
#pragma unroll
        for (int nj = 0; nj < 4; nj++) acc[mi][nj] = zz;

    for (int s = 0; s < 2; s++) {
        int k0 = s * 128;
        __syncthreads();  // prior LDS reads (prev slab / prev job) done
        {
            int side = tid >> 7, r = tid & 127;
            const f32x4* src = (const f32x4*)&X[(size_t)((side ? bj : bi) + r) * F + k0];
            short* dp = (side ? Bbf : Abf) + r * BSTRIDE;
#pragma unroll 4
            for (int j = 0; j < 16; j++) {
                f32x4 v0 = src[2 * j], v1 = src[2 * j + 1];
                short8_t o = {f2bf(v0.x), f2bf(v0.y), f2bf(v0.z), f2bf(v0.w),
                              f2bf(v1.x), f2bf(v1.y), f2bf(v1.z), f2bf(v1.w)};
                *(short8_t*)&dp[j * 8] = o;
            }
        }
        __syncthreads();
#pragma unroll
        for (int s2 = 0; s2 < 4; s2++) {
            short8_t a[4], b[4];
#pragma unroll
            for (int mi = 0; mi < 4; mi++)
                a[mi] = *(const short8_t*)&Abf[(wr * 64 + mi * 16 + l15) * BSTRIDE + s2 * 32 + quad * 8];
#pragma unroll
            for (int nj = 0; nj < 4; nj++)
                b[nj] = *(const short8_t*)&Bbf[(wc * 64 + nj * 16 + l15) * BSTRIDE + s2 * 32 + quad * 8];
#pragma unroll
            for (int mi = 0; mi < 4; mi++)
#pragma unroll
                for (int nj = 0; nj < 4; nj++)
                    acc[mi][nj] = __builtin_amdgcn_mfma_f32_16x16x32_bf16(a[mi], b[nj], acc[mi][nj], 0, 0, 0);
        }
    }

    // epilogue: C/D layout col=lane&15, row=quad*4+reg (m89-verified)
    float sj[4];
#pragma unroll
    for (int nj = 0; nj < 4; nj++) sj[nj] = st[bj + wc * 64 + nj * 16 + l15];
    if (isK) {
#pragma unroll
        for (int mi = 0; mi < 4; mi++) {
#pragma unroll
            for (int reg = 0; reg < 4; reg++) {
                int gi = bi + wr * 64 + mi * 16 + quad * 4 + reg;
                float si = st[gi];
                float* rowp = &dst[(size_t)gi * D + bj + wc * 64 + l15];
#pragma unroll
                for (int nj = 0; nj < 4; nj++)
                    rowp[nj * 16] = __expf(-ALPHA * fmaxf(si + sj[nj] - 2.0f * acc[mi][nj][reg], 0.0f));
            }
        }
    } else {
#pragma unroll
        for (int mi = 0; mi < 4; mi++) {
#pragma unroll
            for (int reg = 0; reg < 4; reg++) {
                int gi = bi + wr * 64 + mi * 16 + quad * 4 + reg;
                float si = st[gi];
                float* rowp = &dst[(size_t)gi * D + bj + wc * 64 + l15];
#pragma unroll
                for (int nj = 0; nj < 4; nj++)
                    rowp[nj * 16] = acc[mi][nj][reg] / (si * sj[nj] + EPSV);
            }
        }
    }
}

__global__ __launch_bounds__(256, 1) void fused4_kernel(
    const float* __restrict__ theta, const float* __restrict__ emb,
    float* __restrict__ Kg, float* __restrict__ Pcg,
    float* __restrict__ sq_g, float* __restrict__ nrm_g, float* __restrict__ rsum_g,
    float* __restrict__ u_g, float* __restrict__ v_g,
    float* __restrict__ err_buf, float* __restrict__ S_buf, float* __restrict__ kl_buf,
    unsigned* __restrict__ gcnt, unsigned* __restrict__ rcnt, unsigned* __restrict__ gen,
    unsigned* __restrict__ magic,
    float* __restrict__ out) {
    extern __shared__ float lds[];
    float* K_lds = lds;                       // loop phase: 16384 floats
    float* red   = lds + 16384;               // overlaps gram region; phase-separated
    short* Abf   = (short*)lds;               // gram: 128 x BSTRIDE bf16
    short* Bbf   = (short*)lds + 128 * BSTRIDE;
    int tid = threadIdx.x, blk = blockIdx.x;
    int rl = tid >> 5, lane = tid & 31;
    int row = blk * RPB + rl;
    unsigned lg = 0;

    // ---- init handshake (ws poisoned 0xAA each launch -> magic != MAGICV) ----
    if (blk == 0 && tid == 0) {
        for (int i = 0; i < 10; i++) err_buf[i] = 0.0f;
        S_buf[0] = 0.0f;
        kl_buf[0] = 0.0f;
        for (int i = 0; i < NGRP; i++) gcnt[i * 16] = 0u;
        *rcnt = 0u;
        __hip_atomic_store(gen, 0u, __ATOMIC_RELAXED, __HIP_MEMORY_SCOPE_AGENT);
        __hip_atomic_store(magic, MAGICV, __ATOMIC_RELEASE, __HIP_MEMORY_SCOPE_AGENT);
    }
    if (tid == 0) {
        while (__hip_atomic_load(magic, __ATOMIC_ACQUIRE, __HIP_MEMORY_SCOPE_AGENT) != MAGICV) {}
    }
    __syncthreads();

    // ---- phase 0: stats for my 8 rows ----
    {
        const f32x4* t4 = (const f32x4*)(theta + (size_t)row * F);
        const f32x4* e4 = (const f32x4*)(emb + (size_t)row * F);
        float s1 = 0.0f, s2 = 0.0f;
        for (int k = lane; k < 64; k += 32) {
            f32x4 a = t4[k];
            s1 = fmaf(a.x, a.x, s1); s1 = fmaf(a.y, a.y, s1);
            s1 = fmaf(a.z, a.z, s1); s1 = fmaf(a.w, a.w, s1);
            f32x4 b = e4[k];
            s2 = fmaf(b.x, b.x, s2); s2 = fmaf(b.y, b.y, s2);
            s2 = fmaf(b.z, b.z, s2); s2 = fmaf(b.w, b.w, s2);
        }
#pragma unroll
        for (int off = 16; off; off >>= 1) {
            s1 += __shfl_xor(s1, off, 32);
            s2 += __shfl_xor(s2, off, 32);
        }
        if (lane == 0) { sq_g[row] = s1; nrm_g[row] = sqrtf(s2); }
    }
    gbar(gcnt, rcnt, gen, lg);

    // ---- phase 1: two 128x128 MFMA gram tile-jobs per block ----
    for (int q = 0; q < 2; q++) {
        int jid = blk * 2 + q;               // 0..511: 256 K tiles then 256 Pc tiles
        int m = jid >> 8, t = jid & 255;
        gram_mfma(m ? emb : theta, m ? nrm_g : sq_g, m ? Pcg : Kg, !m,
                  t >> 4, t & 15, Abf, Bbf);
    }
    gbar(gcnt, rcnt, gen, lg);

    // ---- phase 2: my 8 K rows -> LDS (fp32); rsum of my Pc rows; Ku init ----
    {
        const f32x4* src = (const f32x4*)(Kg + (size_t)blk * RPB * D);
        f32x4* dst4 = (f32x4*)K_lds;
        for (int i = tid; i < RPB * D / 4; i += 256) dst4[i] = src[i];
    }
    {
        const f32x4* p4 = (const f32x4*)(Pcg + (size_t)row * D);
        float s = 0.0f;
        for (int k = lane; k < 512; k += 32) {
            f32x4 v = p4[k];
            s += (v.x + v.y) + (v.z + v.w);
        }
#pragma unroll
        for (int off = 16; off; off >>= 1) s += __shfl_xor(s, off, 32);
        if (lane == 0) rsum_g[row] = s;
    }
    __syncthreads();

    const float bval = 1.0f / (float)D;
    const float aval = 1.0f / (float)D;
    const f32x4* Kr4 = (const f32x4*)(K_lds + rl * D);
    const f32x4* v4 = (const f32x4*)v_g;
    const f32x4* u4 = (const f32x4*)u_g;

    float p = 0.0f;
    for (int k = lane; k < 512; k += 32) {
        f32x4 a = Kr4[k];
        p += (a.x + a.y) + (a.z + a.w);
    }
#pragma unroll
    for (int off = 16; off; off >>= 1) p += __shfl_xor(p, off, 32);
    float Ku = p;

    // ---- Sinkhorn loop (R2-proven exchanges, tree barrier) ----
    float err = 1.0f;
    int cpt = 0;
    float v_r = 0.0f, u_r = 0.0f;
    while (err > STOPTHR && cpt < 500) {
        v_r = bval / (Ku + EPSV);
        if (lane == 0) v_g[row] = v_r;
        gbar(gcnt, rcnt, gen, lg);
        p = 0.0f;
        for (int k = lane; k < 512; k += 32) {
            f32x4 a = Kr4[k];
            f32x4 b = v4[k];
            p = fmaf(a.x, b.x, p); p = fmaf(a.y, b.y, p);
            p = fmaf(a.z, b.z, p); p = fmaf(a.w, b.w, p);
        }
#pragma unroll
        for (int off = 16; off; off >>= 1) p += __shfl_xor(p, off, 32);
        u_r = aval / (p + EPSV);
        if (lane == 0) u_g[row] = u_r;
        gbar(gcnt, rcnt, gen, lg);
        p = 0.0f;
        for (int k = lane; k < 512; k += 32) {
            f32x4 a = Kr4[k];
            f32x4 b = u4[k];
            p = fmaf(a.x, b.x, p); p = fmaf(a.y, b.y, p);
            p = fmaf(a.z, b.z, p); p = fmaf(a.w, b.w, p);
        }
#pragma unroll
        for (int off = 16; off; off >>= 1) p += __shfl_xor(p, off, 32);
        Ku = p;
        cpt++;
        if (cpt % 50 == 1) {
            int chk = cpt / 50;  // 0..9
            float e = fabsf(v_r * Ku - bval);
            e += __shfl_xor(e, 32, 64);
            if ((tid & 63) == 0) atomicAdd(&err_buf[chk], e);
            gbar(gcnt, rcnt, gen, lg);
            err = err_buf[chk];
        }
    }

    // ---- S = sum(max(u_i K_ij v_j, 1e-6)) ----
    float pS = 0.0f;
    for (int k = lane; k < 512; k += 32) {
        f32x4 a = Kr4[k];
        f32x4 b = v4[k];
        pS += fmaxf(u_r * a.x * b.x, 1e-6f) + fmaxf(u_r * a.y * b.y, 1e-6f) +
              fmaxf(u_r * a.z * b.z, 1e-6f) + fmaxf(u_r * a.w * b.w, 1e-6f);
    }
#pragma unroll
    for (int off = 16; off; off >>= 1) pS += __shfl_xor(pS, off, 32);
    pS += __shfl_xor(pS, 32, 64);
    if ((tid & 63) == 0) atomicAdd(S_buf, pS);
    gbar(gcnt, rcnt, gen, lg);
    float logS = __logf(S_buf[0]);

    // ---- KL: P = Pc*0.5*(1/r_i+1/r_j); sum P*(logP-logQc+logS) ----
    float invr_i = 1.0f / rsum_g[row];
    float pkl = 0.0f;
    const f32x4* Pc4 = (const f32x4*)(Pcg + (size_t)row * D);
    const f32x4* rs4 = (const f32x4*)rsum_g;
    for (int k = lane; k < 512; k += 32) {
        f32x4 a = Kr4[k];
        f32x4 b = v4[k];
        f32x4 pc = Pc4[k];
        f32x4 rs = rs4[k];
        float P0 = pc.x * 0.5f * (invr_i + 1.0f / rs.x);
        float P1 = pc.y * 0.5f * (invr_i + 1.0f / rs.y);
        float P2 = pc.z * 0.5f * (invr_i + 1.0f / rs.z);
        float P3 = pc.w * 0.5f * (invr_i + 1.0f / rs.w);
        float q0 = fmaxf(u_r * a.x * b.x, 1e-6f);
        float q1 = fmaxf(u_r * a.y * b.y, 1e-6f);
        float q2 = fmaxf(u_r * a.z * b.z, 1e-6f);
        float q3 = fmaxf(u_r * a.w * b.w, 1e-6f);
        pkl += P0 * (__logf(P0) - __logf(q0) + logS);
        pkl += P1 * (__logf(P1) - __logf(q1) + logS);
        pkl += P2 * (__logf(P2) - __logf(q2) + logS);
        pkl += P3 * (__logf(P3) - __logf(q3) + logS);
    }
#pragma unroll
    for (int off = 16; off; off >>= 1) pkl += __shfl_xor(pkl, off, 32);
    pkl += __shfl_xor(pkl, 32, 64);
    if ((tid & 63) == 0) atomicAdd(kl_buf, pkl);
    gbar(gcnt, rcnt, gen, lg);
    if (blk == 0 && tid == 0) out[0] = kl_buf[0];
}

extern "C" void kernel_launch(void* const* d_in, const int* in_sizes, int n_in,
                              void* d_out, int out_size, void* d_ws, size_t ws_size,
                              hipStream_t stream) {
    const float* theta = (const float*)d_in[0];
    const float* emb = (const float*)d_in[1];
    float* out = (float*)d_out;

    char* ws = (char*)d_ws;
    float* Kg  = (float*)ws;                 // 16 MiB
    float* Pcg = (float*)(ws + (1u << 24));  // 16 MiB
    char* tail = ws + (1u << 25);
    float* err_buf = (float*)(tail);          // 40 B
    float* S_buf   = (float*)(tail + 64);
    float* kl_buf  = (float*)(tail + 128);
    unsigned* rcnt = (unsigned*)(tail + 192);
    unsigned* gen  = (unsigned*)(tail + 256);
    unsigned* magic = (unsigned*)(tail + 320);
    unsigned* gcnt = (unsigned*)(tail + 512); // 8 counters, 64B apart
    float* sq_g   = (float*)(tail + 2048);    // 8 KB each
    float* nrm_g  = (float*)(tail + 2048 + 8192);
    float* rsum_g = (float*)(tail + 2048 + 16384);
    float* u_g    = (float*)(tail + 2048 + 24576);
    float* v_g    = (float*)(tail + 2048 + 32768);

    hipFuncSetAttribute(reinterpret_cast<const void*>(fused4_kernel),
                        hipFuncAttributeMaxDynamicSharedMemorySize, LDS_FLOATS * 4);

    void* kp[] = {(void*)&theta, (void*)&emb, (void*)&Kg, (void*)&Pcg,
                  (void*)&sq_g, (void*)&nrm_g, (void*)&rsum_g,
                  (void*)&u_g, (void*)&v_g,
                  (void*)&err_buf, (void*)&S_buf, (void*)&kl_buf,
                  (void*)&gcnt, (void*)&rcnt, (void*)&gen, (void*)&magic, (void*)&out};
    hipLaunchKernel((void*)fused4_kernel, dim3(NBLK), dim3(256), kp,
                    LDS_FLOATS * sizeof(float), stream);
}

// Round 7
// 280.012 us; speedup vs baseline: 1.0978x; 1.0978x over previous
//
#include <hip/hip_runtime.h>
#include <math.h>

#define D 2048
#define F 256
#define ALPHA 0.005f
#define STOPTHR 0.005f
#define EPSV 1e-16f
#define RPB 8
#define NBLK 256
#define MAGICV 0x13572468u

// Gram phase: 4 bf16 arrays (Ahi,Alo,Bhi,Blo) x 128 rows x 136 shorts = 139,264 B.
// Loop phase: 64 KB K rows. Request max(139264) -> 1 block/CU, grid=256=#CUs,
// all blocks co-resident under a regular launch.
#define BSTRIDE 136
#define LDS_FLOATS 34816

typedef __attribute__((ext_vector_type(8))) short short8_t;
typedef __attribute__((ext_vector_type(4))) float f32x4;

__device__ __forceinline__ short f2bf(float f) {  // RNE float->bf16
    unsigned x = __float_as_uint(f);
    return (short)((x + 0x7fffu + ((x >> 16) & 1u)) >> 16);
}
__device__ __forceinline__ float bf2f(short h) {
    return __uint_as_float(((unsigned)(unsigned short)h) << 16);
}

// ---- central-atomic grid barrier (R2-proven ~1.24 us; beats tree/distributed) ----
__device__ __forceinline__ void gbar(unsigned* cnt, unsigned* gen, unsigned& lg) {
    __syncthreads();
    if (threadIdx.x == 0) {
        unsigned g = lg;
        unsigned a = __hip_atomic_fetch_add(cnt, 1u, __ATOMIC_ACQ_REL, __HIP_MEMORY_SCOPE_AGENT);
        if (a == NBLK - 1) {
            __hip_atomic_store(cnt, 0u, __ATOMIC_RELAXED, __HIP_MEMORY_SCOPE_AGENT);
            __hip_atomic_store(gen, g + 1u, __ATOMIC_RELEASE, __HIP_MEMORY_SCOPE_AGENT);
        } else {
            while ((int)(__hip_atomic_load(gen, __ATOMIC_ACQUIRE, __HIP_MEMORY_SCOPE_AGENT) - (g + 1u)) < 0) {}
        }
    }
    __syncthreads();
    lg++;
}

// ---- 128x128 gram tile via split-bf16 MFMA (hi+lo, 3 terms -> ~fp32 grade) ----
__device__ void gram_mfma(const float* __restrict__ X, const float* __restrict__ st,
                          float* __restrict__ dst, int isK, int ti, int tj,
                          short* __restrict__ Ahi, short* __restrict__ Alo,
                          short* __restrict__ Bhi, short* __restrict__ Blo) {
    int bi = ti * 128, bj = tj * 128;
    int tid = threadIdx.x;
    int w = tid >> 6, l = tid & 63;
    int wr = w >> 1, wc = w & 1;
    int quad = l >> 4, l15 = l & 15;
    f32x4 acc[4][4];
    f32x4 zz = {0.0f, 0.0f, 0.0f, 0.0f};
#pragma unroll
    for (int mi = 0; mi < 4; mi++)
#pragma unroll
        for (int nj = 0; nj < 4; nj++) acc[mi][nj] = zz;

    for (int s = 0; s < 2; s++) {
        int k0 = s * 128;
        __syncthreads();  // prior LDS reads (prev slab / prev job) done
        {
            int side = tid >> 7, r = tid & 127;
            const f32x4* src = (const f32x4*)&X[(size_t)((side ? bj : bi) + r) * F + k0];
            short* dh = (side ? Bhi : Ahi) + r * BSTRIDE;
            short* dl = (side ? Blo : Alo) + r * BSTRIDE;
#pragma unroll 4
            for (int j = 0; j < 16; j++) {
                f32x4 v0 = src[2 * j], v1 = src[2 * j + 1];
                float f[8] = {v0.x, v0.y, v0.z, v0.w, v1.x, v1.y, v1.z, v1.w};
                short8_t oh, ol;
#pragma unroll
                for (int e = 0; e < 8; e++) {
                    short h = f2bf(f[e]);
                    oh[e] = h;
                    ol[e] = f2bf(f[e] - bf2f(h));
                }
                *(short8_t*)&dh[j * 8] = oh;
                *(short8_t*)&dl[j * 8] = ol;
            }
        }
        __syncthreads();
#pragma unroll
        for (int s2 = 0; s2 < 4; s2++) {
            short8_t ah[4], al[4], bh[4], bl[4];
#pragma unroll
            for (int mi = 0; mi < 4; mi++) {
                int off = (wr * 64 + mi * 16 + l15) * BSTRIDE + s2 * 32 + quad * 8;
                ah[mi] = *(const short8_t*)&Ahi[off];
                al[mi] = *(const short8_t*)&Alo[off];
            }
#pragma unroll
            for (int nj = 0; nj < 4; nj++) {
                int off = (wc * 64 + nj * 16 + l15) * BSTRIDE + s2 * 32 + quad * 8;
                bh[nj] = *(const short8_t*)&Bhi[off];
                bl[nj] = *(const short8_t*)&Blo[off];
            }
#pragma unroll
            for (int mi = 0; mi < 4; mi++)
#pragma unroll
                for (int nj = 0; nj < 4; nj++) {
                    acc[mi][nj] = __builtin_amdgcn_mfma_f32_16x16x32_bf16(ah[mi], bh[nj], acc[mi][nj], 0, 0, 0);
                    acc[mi][nj] = __builtin_amdgcn_mfma_f32_16x16x32_bf16(ah[mi], bl[nj], acc[mi][nj], 0, 0, 0);
                    acc[mi][nj] = __builtin_amdgcn_mfma_f32_16x16x32_bf16(al[mi], bh[nj], acc[mi][nj], 0, 0, 0);
                }
        }
    }

    // epilogue: C/D layout col=lane&15, row=quad*4+reg (m89-verified)
    float sj[4];
#pragma unroll
    for (int nj = 0; nj < 4; nj++) sj[nj] = st[bj + wc * 64 + nj * 16 + l15];
    if (isK) {
#pragma unroll
        for (int mi = 0; mi < 4; mi++) {
#pragma unroll
            for (int reg = 0; reg < 4; reg++) {
                int gi = bi + wr * 64 + mi * 16 + quad * 4 + reg;
                float si = st[gi];
                float* rowp = &dst[(size_t)gi * D + bj + wc * 64 + l15];
#pragma unroll
                for (int nj = 0; nj < 4; nj++)
                    rowp[nj * 16] = __expf(-ALPHA * fmaxf(si + sj[nj] - 2.0f * acc[mi][nj][reg], 0.0f));
            }
        }
    } else {
#pragma unroll
        for (int mi = 0; mi < 4; mi++) {
#pragma unroll
            for (int reg = 0; reg < 4; reg++) {
                int gi = bi + wr * 64 + mi * 16 + quad * 4 + reg;
                float si = st[gi];
                float* rowp = &dst[(size_t)gi * D + bj + wc * 64 + l15];
#pragma unroll
                for (int nj = 0; nj < 4; nj++)
                    rowp[nj * 16] = acc[mi][nj][reg] / (si * sj[nj] + EPSV);
            }
        }
    }
}

__global__ __launch_bounds__(256, 1) void fused5_kernel(
    const float* __restrict__ theta, const float* __restrict__ emb,
    float* __restrict__ Kg, float* __restrict__ Pcg,
    float* __restrict__ sq_g, float* __restrict__ nrm_g, float* __restrict__ rsum_g,
    float* __restrict__ u_g, float* __restrict__ v_g,
    float* __restrict__ err_buf, float* __restrict__ S_buf, float* __restrict__ kl_buf,
    unsigned* __restrict__ bar_cnt, unsigned* __restrict__ bar_gen,
    unsigned* __restrict__ magic,
    float* __restrict__ out) {
    extern __shared__ float lds[];
    float* K_lds = lds;                             // loop phase: 16384 floats
    short* Ahi = (short*)lds;                       // gram phase: 4 x 128 x BSTRIDE
    short* Alo = Ahi + 128 * BSTRIDE;
    short* Bhi = Alo + 128 * BSTRIDE;
    short* Blo = Bhi + 128 * BSTRIDE;
    int tid = threadIdx.x, blk = blockIdx.x;
    int rl = tid >> 5, lane = tid & 31;
    int row = blk * RPB + rl;
    unsigned lg = 0;

    // ---- init handshake (ws poisoned 0xAA each launch -> magic != MAGICV) ----
    if (blk == 0 && tid == 0) {
        for (int i = 0; i < 10; i++) err_buf[i] = 0.0f;
        S_buf[0] = 0.0f;
        kl_buf[0] = 0.0f;
        *bar_cnt = 0u;
        __hip_atomic_store(bar_gen, 0u, __ATOMIC_RELAXED, __HIP_MEMORY_SCOPE_AGENT);
        __hip_atomic_store(magic, MAGICV, __ATOMIC_RELEASE, __HIP_MEMORY_SCOPE_AGENT);
    }
    if (tid == 0) {
        while (__hip_atomic_load(magic, __ATOMIC_ACQUIRE, __HIP_MEMORY_SCOPE_AGENT) != MAGICV) {}
    }
    __syncthreads();

    // ---- phase 0: stats for my 8 rows ----
    {
        const f32x4* t4 = (const f32x4*)(theta + (size_t)row * F);
        const f32x4* e4 = (const f32x4*)(emb + (size_t)row * F);
        float s1 = 0.0f, s2 = 0.0f;
        for (int k = lane; k < 64; k += 32) {
            f32x4 a = t4[k];
            s1 = fmaf(a.x, a.x, s1); s1 = fmaf(a.y, a.y, s1);
            s1 = fmaf(a.z, a.z, s1); s1 = fmaf(a.w, a.w, s1);
            f32x4 b = e4[k];
            s2 = fmaf(b.x, b.x, s2); s2 = fmaf(b.y, b.y, s2);
            s2 = fmaf(b.z, b.z, s2); s2 = fmaf(b.w, b.w, s2);
        }
#pragma unroll
        for (int off = 16; off; off >>= 1) {
            s1 += __shfl_xor(s1, off, 32);
            s2 += __shfl_xor(s2, off, 32);
        }
        if (lane == 0) { sq_g[row] = s1; nrm_g[row] = sqrtf(s2); }
    }
    gbar(bar_cnt, bar_gen, lg);

    // ---- phase 1: two 128x128 split-bf16 MFMA gram tile-jobs per block ----
    for (int q = 0; q < 2; q++) {
        int jid = blk * 2 + q;               // 0..511: 256 K tiles then 256 Pc tiles
        int m = jid >> 8, t = jid & 255;
        gram_mfma(m ? emb : theta, m ? nrm_g : sq_g, m ? Pcg : Kg, !m,
                  t >> 4, t & 15, Ahi, Alo, Bhi, Blo);
    }
    gbar(bar_cnt, bar_gen, lg);

    // ---- phase 2: my 8 K rows -> LDS (fp32); rsum of my Pc rows; Ku init ----
    {
        const f32x4* src = (const f32x4*)(Kg + (size_t)blk * RPB * D);
        f32x4* dst4 = (f32x4*)K_lds;
        for (int i = tid; i < RPB * D / 4; i += 256) dst4[i] = src[i];
    }
    {
        const f32x4* p4 = (const f32x4*)(Pcg + (size_t)row * D);
        float s = 0.0f;
        for (int k = lane; k < 512; k += 32) {
            f32x4 v = p4[k];
            s += (v.x + v.y) + (v.z + v.w);
        }
#pragma unroll
        for (int off = 16; off; off >>= 1) s += __shfl_xor(s, off, 32);
        if (lane == 0) rsum_g[row] = s;
    }
    __syncthreads();

    const float bval = 1.0f / (float)D;
    const float aval = 1.0f / (float)D;
    const f32x4* Kr4 = (const f32x4*)(K_lds + rl * D);
    const f32x4* v4 = (const f32x4*)v_g;
    const f32x4* u4 = (const f32x4*)u_g;

    float p = 0.0f;
    for (int k = lane; k < 512; k += 32) {
        f32x4 a = Kr4[k];
        p += (a.x + a.y) + (a.z + a.w);
    }
#pragma unroll
    for (int off = 16; off; off >>= 1) p += __shfl_xor(p, off, 32);
    float Ku = p;

    // ---- Sinkhorn loop (R2-proven structure + central gbar) ----
    float err = 1.0f;
    int cpt = 0;
    float v_r = 0.0f, u_r = 0.0f;
    while (err > STOPTHR && cpt < 500) {
        v_r = bval / (Ku + EPSV);
        if (lane == 0) v_g[row] = v_r;
        gbar(bar_cnt, bar_gen, lg);
        p = 0.0f;
        for (int k = lane; k < 512; k += 32) {
            f32x4 a = Kr4[k];
            f32x4 b = v4[k];
            p = fmaf(a.x, b.x, p); p = fmaf(a.y, b.y, p);
            p = fmaf(a.z, b.z, p); p = fmaf(a.w, b.w, p);
        }
#pragma unroll
        for (int off = 16; off; off >>= 1) p += __shfl_xor(p, off, 32);
        u_r = aval / (p + EPSV);
        if (lane == 0) u_g[row] = u_r;
        gbar(bar_cnt, bar_gen, lg);
        p = 0.0f;
        for (int k = lane; k < 512; k += 32) {
            f32x4 a = Kr4[k];
            f32x4 b = u4[k];
            p = fmaf(a.x, b.x, p); p = fmaf(a.y, b.y, p);
            p = fmaf(a.z, b.z, p); p = fmaf(a.w, b.w, p);
        }
#pragma unroll
        for (int off = 16; off; off >>= 1) p += __shfl_xor(p, off, 32);
        Ku = p;
        cpt++;
        if (cpt % 50 == 1) {
            int chk = cpt / 50;  // 0..9
            float e = fabsf(v_r * Ku - bval);
            e += __shfl_xor(e, 32, 64);
            if ((tid & 63) == 0) atomicAdd(&err_buf[chk], e);
            gbar(bar_cnt, bar_gen, lg);
            err = err_buf[chk];
        }
    }

    // ---- S = sum(max(u_i K_ij v_j, 1e-6)) ----
    float pS = 0.0f;
    for (int k = lane; k < 512; k += 32) {
        f32x4 a = Kr4[k];
        f32x4 b = v4[k];
        pS += fmaxf(u_r * a.x * b.x, 1e-6f) + fmaxf(u_r * a.y * b.y, 1e-6f) +
              fmaxf(u_r * a.z * b.z, 1e-6f) + fmaxf(u_r * a.w * b.w, 1e-6f);
    }
#pragma unroll
    for (int off = 16; off; off >>= 1) pS += __shfl_xor(pS, off, 32);
    pS += __shfl_xor(pS, 32, 64);
    if ((tid & 63) == 0) atomicAdd(S_buf, pS);
    gbar(bar_cnt, bar_gen, lg);
    float logS = __logf(S_buf[0]);

    // ---- KL: P = Pc*0.5*(1/r_i+1/r_j); sum P*(logP-logQc+logS) ----
    float invr_i = 1.0f / rsum_g[row];
    float pkl = 0.0f;
    const f32x4* Pc4 = (const f32x4*)(Pcg + (size_t)row * D);
    const f32x4* rs4 = (const f32x4*)rsum_g;
    for (int k = lane; k < 512; k += 32) {
        f32x4 a = Kr4[k];
        f32x4 b = v4[k];
        f32x4 pc = Pc4[k];
        f32x4 rs = rs4[k];
        float P0 = pc.x * 0.5f * (invr_i + 1.0f / rs.x);
        float P1 = pc.y * 0.5f * (invr_i + 1.0f / rs.y);
        float P2 = pc.z * 0.5f * (invr_i + 1.0f / rs.z);
        float P3 = pc.w * 0.5f * (invr_i + 1.0f / rs.w);
        float q0 = fmaxf(u_r * a.x * b.x, 1e-6f);
        float q1 = fmaxf(u_r * a.y * b.y, 1e-6f);
        float q2 = fmaxf(u_r * a.z * b.z, 1e-6f);
        float q3 = fmaxf(u_r * a.w * b.w, 1e-6f);
        pkl += P0 * (__logf(P0) - __logf(q0) + logS);
        pkl += P1 * (__logf(P1) - __logf(q1) + logS);
        pkl += P2 * (__logf(P2) - __logf(q2) + logS);
        pkl += P3 * (__logf(P3) - __logf(q3) + logS);
    }
#pragma unroll
    for (int off = 16; off; off >>= 1) pkl += __shfl_xor(pkl, off, 32);
    pkl += __shfl_xor(pkl, 32, 64);
    if ((tid & 63) == 0) atomicAdd(kl_buf, pkl);
    gbar(bar_cnt, bar_gen, lg);
    if (blk == 0 && tid == 0) out[0] = kl_buf[0];
}

extern "C" void kernel_launch(void* const* d_in, const int* in_sizes, int n_in,
                              void* d_out, int out_size, void* d_ws, size_t ws_size,
                              hipStream_t stream) {
    const float* theta = (const float*)d_in[0];
    const float* emb = (const float*)d_in[1];
    float* out = (float*)d_out;

    char* ws = (char*)d_ws;
    float* Kg  = (float*)ws;                 // 16 MiB
    float* Pcg = (float*)(ws + (1u << 24));  // 16 MiB
    char* tail = ws + (1u << 25);
    float* err_buf = (float*)(tail);          // 40 B
    float* S_buf   = (float*)(tail + 64);
    float* kl_buf  = (float*)(tail + 128);
    unsigned* bar_cnt = (unsigned*)(tail + 192);
    unsigned* bar_gen = (unsigned*)(tail + 256);
    unsigned* magic   = (unsigned*)(tail + 320);
    float* sq_g   = (float*)(tail + 1024);    // 8 KB each
    float* nrm_g  = (float*)(tail + 1024 + 8192);
    float* rsum_g = (float*)(tail + 1024 + 16384);
    float* u_g    = (float*)(tail + 1024 + 24576);
    float* v_g    = (float*)(tail + 1024 + 32768);

    hipFuncSetAttribute(reinterpret_cast<const void*>(fused5_kernel),
                        hipFuncAttributeMaxDynamicSharedMemorySize, LDS_FLOATS * 4);

    void* kp[] = {(void*)&theta, (void*)&emb, (void*)&Kg, (void*)&Pcg,
                  (void*)&sq_g, (void*)&nrm_g, (void*)&rsum_g,
                  (void*)&u_g, (void*)&v_g,
                  (void*)&err_buf, (void*)&S_buf, (void*)&kl_buf,
                  (void*)&bar_cnt, (void*)&bar_gen, (void*)&magic, (void*)&out};
    hipLaunchKernel((void*)fused5_kernel, dim3(NBLK), dim3(256), kp,
                    LDS_FLOATS * sizeof(float), stream);
}